// Round 4
// baseline (435.031 us; speedup 1.0000x reference)
//
#include <hip/hip_runtime.h>
#include <math.h>

// Softmax splatting: B=8, C=4, H=512, W=960, fp32.
// Owner-computes: each block owns a 32x32 OUTPUT tile, gathers all sources
// within +-RAD, scatters corners into an LDS accumulator, normalizes, stores.
// R4: explicit ILP — branch-free load phase (49 loads in flight) + process phase.

#define EPS 1e-7f

constexpr int B = 8, C = 4, H = 512, W = 960;
constexpr int HW = H * W;            // 491520
constexpr int CHW = C * HW;          // 1966080
constexpr int NPIX = B * HW;         // 3932160

constexpr int TX = 32, TY = 32;      // output tile
constexpr int RAD = 5;               // coverage box half-width
constexpr int RX = TX + 2 * RAD;     // 42
constexpr int RY = TY + 2 * RAD;     // 42
constexpr int RCELLS = RX * RY;      // 1764
constexpr int NITER = (RCELLS + 255) / 256;   // 7

constexpr int OVF_CAP = 480000;      // 480K entries * 32B = 15.36 MB in d_ws

// ---- prepass: sources whose corners escape the +-RAD box -> overflow list
__global__ __launch_bounds__(256) void outlier_pass(
    const float* __restrict__ frame,
    const float* __restrict__ flow,
    const float* __restrict__ imp,
    int* __restrict__ ovf_cnt,
    float* __restrict__ ovf_buf)
{
    int idx = blockIdx.x * blockDim.x + threadIdx.x;
    if (idx >= NPIX) return;
    int b = idx / HW;
    int p = idx - b * HW;
    int sy = p / W;
    int sx = p - sy * W;

    const size_t flb = (size_t)b * 2 * HW;
    float flx = flow[flb + p];
    float fly = flow[flb + HW + p];

    // |fl| <= RAD-1 guarantees both corners within +-RAD box
    if (fabsf(flx) <= (float)(RAD - 1) && fabsf(fly) <= (float)(RAD - 1)) return;

    float tx = (float)sx + flx;
    float ty = (float)sy + fly;
    float fxf = floorf(tx);
    float fyf = floorf(ty);
    float dx = tx - fxf;
    float dy = ty - fyf;
    int fx = (int)fxf;
    int fy = (int)fyf;

    const size_t fb = (size_t)b * CHW;
    float im = __expf(imp[(size_t)b * HW + p]);
    float f0 = frame[fb + 0 * HW + p] * im;
    float f1 = frame[fb + 1 * HW + p] * im;
    float f2 = frame[fb + 2 * HW + p] * im;
    float f3 = frame[fb + 3 * HW + p] * im;

    #pragma unroll
    for (int cyi = 0; cyi < 2; ++cyi) {
        #pragma unroll
        for (int cxi = 0; cxi < 2; ++cxi) {
            int cx = fx + cxi;
            int cy = fy + cyi;
            if ((unsigned)cx >= (unsigned)W || (unsigned)cy >= (unsigned)H) continue;
            int ax = cx - sx; if (ax < 0) ax = -ax;
            int ay = cy - sy; if (ay < 0) ay = -ay;
            if (ax <= RAD && ay <= RAD) continue;   // covered by owner block
            float w = (cxi ? dx : 1.0f - dx) * (cyi ? dy : 1.0f - dy);
            int e = atomicAdd(ovf_cnt, 1);
            if (e < OVF_CAP) {
                float* ent = ovf_buf + (size_t)e * 8;
                ent[0] = __int_as_float(b * HW + cy * W + cx);
                ent[1] = f0 * w;
                ent[2] = f1 * w;
                ent[3] = f2 * w;
                ent[4] = f3 * w;
                ent[5] = im * w;
            }
        }
    }
}

// ---- main: per-output-tile gather-scatter + fused normalize
__global__ __launch_bounds__(256) void splat_main(
    const float* __restrict__ frame,
    const float* __restrict__ flow,
    const float* __restrict__ imp,
    float* __restrict__ out,
    const int* __restrict__ ovf_cnt,
    const float* __restrict__ ovf_buf)
{
    __shared__ float lf[5 * TX * TY];   // 20480 B

    const int tid = threadIdx.x;
    const int x0 = blockIdx.x * TX;
    const int y0 = blockIdx.y * TY;
    const int b  = blockIdx.z;

    for (int i = tid; i < 5 * TX * TY; i += 256) lf[i] = 0.0f;
    __syncthreads();

    const size_t fb  = (size_t)b * CHW;
    const size_t flb = (size_t)b * 2 * HW;
    const size_t ib  = (size_t)b * HW;

    // ---------- load phase: NITER cells/thread, branch-free, all loads batched
    float flx[NITER], fly[NITER], imv[NITER];
    float fr0[NITER], fr1[NITER], fr2[NITER], fr3[NITER];

    #pragma unroll
    for (int k = 0; k < NITER; ++k) {
        int i = tid + k * 256;
        int ly = i / RX;
        int lx = i - ly * RX;
        int sx = x0 - RAD + lx;
        int sy = y0 - RAD + ly;
        bool v = (i < RCELLS) & ((unsigned)sx < (unsigned)W) & ((unsigned)sy < (unsigned)H);
        int p = v ? sy * W + sx : 0;
        flx[k] = flow[flb + p];
        fly[k] = flow[flb + HW + p];
        float e = __expf(imp[ib + p]);
        imv[k] = v ? e : 0.0f;             // OOB/pad cells contribute exactly zero
        fr0[k] = frame[fb + 0 * HW + p];
        fr1[k] = frame[fb + 1 * HW + p];
        fr2[k] = frame[fb + 2 * HW + p];
        fr3[k] = frame[fb + 3 * HW + p];
    }

    // ---------- process phase: corner scatter into LDS
    #pragma unroll
    for (int k = 0; k < NITER; ++k) {
        int i = tid + k * 256;
        int ly = i / RX;
        int lx = i - ly * RX;
        int sx = x0 - RAD + lx;
        int sy = y0 - RAD + ly;

        float tx = (float)sx + flx[k];
        float ty = (float)sy + fly[k];
        float fxf = floorf(tx);
        float fyf = floorf(ty);
        float dx = tx - fxf;
        float dy = ty - fyf;
        int fx = (int)fxf;
        int fy = (int)fyf;

        float im = imv[k];
        float g0 = fr0[k] * im;
        float g1 = fr1[k] * im;
        float g2 = fr2[k] * im;
        float g3 = fr3[k] * im;

        #pragma unroll
        for (int cyi = 0; cyi < 2; ++cyi) {
            #pragma unroll
            for (int cxi = 0; cxi < 2; ++cxi) {
                int cx = fx + cxi;
                int cy = fy + cyi;
                int lxc = cx - x0;
                int lyc = cy - y0;
                int ax = cx - sx; if (ax < 0) ax = -ax;
                int ay = cy - sy; if (ay < 0) ay = -ay;
                bool in = ((unsigned)lxc < (unsigned)TX) & ((unsigned)lyc < (unsigned)TY)
                        & (ax <= RAD) & (ay <= RAD);
                if (in) {
                    float w = (cxi ? dx : 1.0f - dx) * (cyi ? dy : 1.0f - dy);
                    int cell = lyc * TX + lxc;
                    atomicAdd(&lf[0 * 1024 + cell], g0 * w);
                    atomicAdd(&lf[1 * 1024 + cell], g1 * w);
                    atomicAdd(&lf[2 * 1024 + cell], g2 * w);
                    atomicAdd(&lf[3 * 1024 + cell], g3 * w);
                    atomicAdd(&lf[4 * 1024 + cell], im * w);
                }
            }
        }
    }

    // ---------- merge overflow entries that land in my tile
    int cnt = *ovf_cnt;
    if (cnt > OVF_CAP) cnt = OVF_CAP;
    for (int e = tid; e < cnt; e += 256) {
        const float* ent = ovf_buf + (size_t)e * 8;
        int bcell = __float_as_int(ent[0]);
        int eb = bcell / HW;
        if (eb != b) continue;
        int rem = bcell - eb * HW;
        int cy = rem / W;
        int cx = rem - cy * W;
        int lxc = cx - x0;
        int lyc = cy - y0;
        if ((unsigned)lxc >= (unsigned)TX || (unsigned)lyc >= (unsigned)TY) continue;
        int cell = lyc * TX + lxc;
        atomicAdd(&lf[0 * 1024 + cell], ent[1]);
        atomicAdd(&lf[1 * 1024 + cell], ent[2]);
        atomicAdd(&lf[2 * 1024 + cell], ent[3]);
        atomicAdd(&lf[3 * 1024 + cell], ent[4]);
        atomicAdd(&lf[4 * 1024 + cell], ent[5]);
    }

    __syncthreads();

    // ---------- fused normalize + store
    #pragma unroll
    for (int n = 0; n < (TX * TY) / 256; ++n) {
        int i = tid + n * 256;
        int cy = i >> 5;
        int cx = i & 31;
        float inv = 1.0f / (lf[4 * 1024 + i] + EPS);
        size_t o = fb + (size_t)(y0 + cy) * W + (x0 + cx);
        out[o + 0 * HW] = lf[0 * 1024 + i] * inv;
        out[o + 1 * HW] = lf[1 * 1024 + i] * inv;
        out[o + 2 * HW] = lf[2 * 1024 + i] * inv;
        out[o + 3 * HW] = lf[3 * 1024 + i] * inv;
    }
}

extern "C" void kernel_launch(void* const* d_in, const int* in_sizes, int n_in,
                              void* d_out, int out_size, void* d_ws, size_t ws_size,
                              hipStream_t stream) {
    const float* frame = (const float*)d_in[0];
    const float* flow  = (const float*)d_in[1];
    const float* imp   = (const float*)d_in[2];
    float* out = (float*)d_out;

    int*   ovf_cnt = (int*)d_ws;
    float* ovf_buf = (float*)((char*)d_ws + 16);

    hipMemsetAsync(d_ws, 0, 16, stream);   // just the counter

    outlier_pass<<<(NPIX + 255) / 256, 256, 0, stream>>>(frame, flow, imp, ovf_cnt, ovf_buf);

    dim3 grid(W / TX, H / TY, B);   // 30 x 16 x 8
    splat_main<<<grid, 256, 0, stream>>>(frame, flow, imp, out, ovf_cnt, ovf_buf);
}

// Round 5
// 419.522 us; speedup vs baseline: 1.0370x; 1.0370x over previous
//
#include <hip/hip_runtime.h>
#include <math.h>

// Softmax splatting: B=8, C=4, H=512, W=960, fp32.
// Owner-computes: each block owns a 32x32 OUTPUT tile, gathers all sources
// within +-RAD, scatters corners into an LDS accumulator (native ds_add_f32
// via unsafeAtomicAdd), normalizes, stores. No global atomics in main path.

#define EPS 1e-7f

constexpr int B = 8, C = 4, H = 512, W = 960;
constexpr int HW = H * W;            // 491520
constexpr int CHW = C * HW;          // 1966080
constexpr int NPIX = B * HW;         // 3932160

constexpr int TX = 32, TY = 32;      // output tile
constexpr int RAD = 5;               // coverage box half-width
constexpr int RX = TX + 2 * RAD;     // 42
constexpr int RY = TY + 2 * RAD;     // 42
constexpr int RCELLS = RX * RY;      // 1764

constexpr int OVF_CAP = 480000;      // 480K entries * 32B = 15.36 MB in d_ws

// native LDS float add (ds_add_f32), not the safe CAS loop
__device__ __forceinline__ void lds_add(float* p, float v) {
    unsafeAtomicAdd(p, v);
}

// ---- prepass: sources whose corners escape the +-RAD box -> overflow list
__global__ __launch_bounds__(256) void outlier_pass(
    const float* __restrict__ frame,
    const float* __restrict__ flow,
    const float* __restrict__ imp,
    int* __restrict__ ovf_cnt,
    float* __restrict__ ovf_buf)
{
    int idx = blockIdx.x * blockDim.x + threadIdx.x;
    if (idx >= NPIX) return;
    int b = idx / HW;
    int p = idx - b * HW;
    int sy = p / W;
    int sx = p - sy * W;

    const size_t flb = (size_t)b * 2 * HW;
    float flx = flow[flb + p];
    float fly = flow[flb + HW + p];

    // |fl| <= RAD-1 guarantees both corners within +-RAD box
    if (fabsf(flx) <= (float)(RAD - 1) && fabsf(fly) <= (float)(RAD - 1)) return;

    float tx = (float)sx + flx;
    float ty = (float)sy + fly;
    float fxf = floorf(tx);
    float fyf = floorf(ty);
    float dx = tx - fxf;
    float dy = ty - fyf;
    int fx = (int)fxf;
    int fy = (int)fyf;

    const size_t fb = (size_t)b * CHW;
    float im = __expf(imp[(size_t)b * HW + p]);
    float f0 = frame[fb + 0 * HW + p] * im;
    float f1 = frame[fb + 1 * HW + p] * im;
    float f2 = frame[fb + 2 * HW + p] * im;
    float f3 = frame[fb + 3 * HW + p] * im;

    #pragma unroll
    for (int cyi = 0; cyi < 2; ++cyi) {
        #pragma unroll
        for (int cxi = 0; cxi < 2; ++cxi) {
            int cx = fx + cxi;
            int cy = fy + cyi;
            if ((unsigned)cx >= (unsigned)W || (unsigned)cy >= (unsigned)H) continue;
            int ax = cx - sx; if (ax < 0) ax = -ax;
            int ay = cy - sy; if (ay < 0) ay = -ay;
            if (ax <= RAD && ay <= RAD) continue;   // covered by owner block
            float w = (cxi ? dx : 1.0f - dx) * (cyi ? dy : 1.0f - dy);
            int e = atomicAdd(ovf_cnt, 1);
            if (e < OVF_CAP) {
                float* ent = ovf_buf + (size_t)e * 8;
                ent[0] = __int_as_float(b * HW + cy * W + cx);
                ent[1] = f0 * w;
                ent[2] = f1 * w;
                ent[3] = f2 * w;
                ent[4] = f3 * w;
                ent[5] = im * w;
            }
        }
    }
}

// ---- main: per-output-tile gather-scatter + fused normalize
__global__ __launch_bounds__(256) void splat_main(
    const float* __restrict__ frame,
    const float* __restrict__ flow,
    const float* __restrict__ imp,
    float* __restrict__ out,
    const int* __restrict__ ovf_cnt,
    const float* __restrict__ ovf_buf)
{
    __shared__ float lf[5 * TX * TY];   // 20480 B

    const int tid = threadIdx.x;
    const int x0 = blockIdx.x * TX;
    const int y0 = blockIdx.y * TY;
    const int b  = blockIdx.z;

    for (int i = tid; i < 5 * TX * TY; i += 256) lf[i] = 0.0f;
    __syncthreads();

    const size_t fb  = (size_t)b * CHW;
    const size_t flb = (size_t)b * 2 * HW;
    const size_t ib  = (size_t)b * HW;

    // scatter: all sources whose +-RAD coverage box can touch my tile
    for (int i = tid; i < RCELLS; i += 256) {
        int ly = i / RX;
        int lx = i - ly * RX;
        int sx = x0 - RAD + lx;
        int sy = y0 - RAD + ly;
        if ((unsigned)sx >= (unsigned)W || (unsigned)sy >= (unsigned)H) continue;
        int p = sy * W + sx;

        float flx = flow[flb + p];
        float fly = flow[flb + HW + p];
        float im  = __expf(imp[ib + p]);

        float tx = (float)sx + flx;
        float ty = (float)sy + fly;
        float fxf = floorf(tx);
        float fyf = floorf(ty);
        float dx = tx - fxf;
        float dy = ty - fyf;
        int fx = (int)fxf;
        int fy = (int)fyf;

        float f0 = frame[fb + 0 * HW + p] * im;
        float f1 = frame[fb + 1 * HW + p] * im;
        float f2 = frame[fb + 2 * HW + p] * im;
        float f3 = frame[fb + 3 * HW + p] * im;

        #pragma unroll
        for (int cyi = 0; cyi < 2; ++cyi) {
            #pragma unroll
            for (int cxi = 0; cxi < 2; ++cxi) {
                int cx = fx + cxi;
                int cy = fy + cyi;
                int lxc = cx - x0;
                int lyc = cy - y0;
                if ((unsigned)lxc >= (unsigned)TX || (unsigned)lyc >= (unsigned)TY) continue;
                int ax = cx - sx; if (ax < 0) ax = -ax;
                int ay = cy - sy; if (ay < 0) ay = -ay;
                if (ax > RAD || ay > RAD) continue;     // overflow list handles
                float w = (cxi ? dx : 1.0f - dx) * (cyi ? dy : 1.0f - dy);
                int cell = lyc * TX + lxc;
                lds_add(&lf[0 * 1024 + cell], f0 * w);
                lds_add(&lf[1 * 1024 + cell], f1 * w);
                lds_add(&lf[2 * 1024 + cell], f2 * w);
                lds_add(&lf[3 * 1024 + cell], f3 * w);
                lds_add(&lf[4 * 1024 + cell], im * w);
            }
        }
    }

    // merge overflow entries that land in my tile
    int cnt = *ovf_cnt;
    if (cnt > OVF_CAP) cnt = OVF_CAP;
    for (int e = tid; e < cnt; e += 256) {
        const float* ent = ovf_buf + (size_t)e * 8;
        int bcell = __float_as_int(ent[0]);
        int eb = bcell / HW;
        if (eb != b) continue;
        int rem = bcell - eb * HW;
        int cy = rem / W;
        int cx = rem - cy * W;
        int lxc = cx - x0;
        int lyc = cy - y0;
        if ((unsigned)lxc >= (unsigned)TX || (unsigned)lyc >= (unsigned)TY) continue;
        int cell = lyc * TX + lxc;
        lds_add(&lf[0 * 1024 + cell], ent[1]);
        lds_add(&lf[1 * 1024 + cell], ent[2]);
        lds_add(&lf[2 * 1024 + cell], ent[3]);
        lds_add(&lf[3 * 1024 + cell], ent[4]);
        lds_add(&lf[4 * 1024 + cell], ent[5]);
    }

    __syncthreads();

    // fused normalize + store
    #pragma unroll
    for (int n = 0; n < (TX * TY) / 256; ++n) {
        int i = tid + n * 256;
        int cy = i >> 5;
        int cx = i & 31;
        float inv = 1.0f / (lf[4 * 1024 + i] + EPS);
        size_t o = fb + (size_t)(y0 + cy) * W + (x0 + cx);
        out[o + 0 * HW] = lf[0 * 1024 + i] * inv;
        out[o + 1 * HW] = lf[1 * 1024 + i] * inv;
        out[o + 2 * HW] = lf[2 * 1024 + i] * inv;
        out[o + 3 * HW] = lf[3 * 1024 + i] * inv;
    }
}

extern "C" void kernel_launch(void* const* d_in, const int* in_sizes, int n_in,
                              void* d_out, int out_size, void* d_ws, size_t ws_size,
                              hipStream_t stream) {
    const float* frame = (const float*)d_in[0];
    const float* flow  = (const float*)d_in[1];
    const float* imp   = (const float*)d_in[2];
    float* out = (float*)d_out;

    int*   ovf_cnt = (int*)d_ws;
    float* ovf_buf = (float*)((char*)d_ws + 16);

    hipMemsetAsync(d_ws, 0, 16, stream);   // just the counter

    outlier_pass<<<(NPIX + 255) / 256, 256, 0, stream>>>(frame, flow, imp, ovf_cnt, ovf_buf);

    dim3 grid(W / TX, H / TY, B);   // 30 x 16 x 8
    splat_main<<<grid, 256, 0, stream>>>(frame, flow, imp, out, ovf_cnt, ovf_buf);
}

// Round 6
// 416.872 us; speedup vs baseline: 1.0436x; 1.0064x over previous
//
#include <hip/hip_runtime.h>
#include <math.h>

// Softmax splatting: B=8, C=4, H=512, W=960, fp32.
// Owner-computes 32x32 output tiles; float4-vectorized gather of the
// 48x42 source region (quad = 4 consecutive x cells), LDS ds_add_f32
// scatter, fused normalize+store. Overflow list handles |flow|>RAD.

#define EPS 1e-7f

constexpr int B = 8, C = 4, H = 512, W = 960;
constexpr int HW = H * W;            // 491520
constexpr int CHW = C * HW;          // 1966080
constexpr int NPIX = B * HW;         // 3932160

constexpr int TX = 32, TY = 32;      // output tile
constexpr int RAD = 5;               // coverage box half-width
constexpr int GX = 48;               // region cols: x in [x0-8, x0+40), 16B aligned
constexpr int GY = TY + 2 * RAD;     // 42 rows:    y in [y0-5, y0+37)
constexpr int QX = GX / 4;           // 12 quads per row
constexpr int NQUAD = QX * GY;       // 504 quads per block

constexpr int OVF_CAP = 480000;      // 480K entries * 32B = 15.36 MB in d_ws

__device__ __forceinline__ void lds_add(float* p, float v) {
    unsafeAtomicAdd(p, v);           // native ds_add_f32
}

// ---- prepass: sources whose corners escape the +-RAD box -> overflow list
__global__ __launch_bounds__(256) void outlier_pass(
    const float* __restrict__ frame,
    const float* __restrict__ flow,
    const float* __restrict__ imp,
    int* __restrict__ ovf_cnt,
    float* __restrict__ ovf_buf)
{
    int idx = blockIdx.x * blockDim.x + threadIdx.x;
    if (idx >= NPIX) return;
    int b = idx / HW;
    int p = idx - b * HW;
    int sy = p / W;
    int sx = p - sy * W;

    const size_t flb = (size_t)b * 2 * HW;
    float flx = flow[flb + p];
    float fly = flow[flb + HW + p];

    // |fl| <= RAD-1 guarantees both corners within +-RAD box
    if (fabsf(flx) <= (float)(RAD - 1) && fabsf(fly) <= (float)(RAD - 1)) return;

    float tx = (float)sx + flx;
    float ty = (float)sy + fly;
    float fxf = floorf(tx);
    float fyf = floorf(ty);
    float dx = tx - fxf;
    float dy = ty - fyf;
    int fx = (int)fxf;
    int fy = (int)fyf;

    const size_t fb = (size_t)b * CHW;
    float im = __expf(imp[(size_t)b * HW + p]);
    float f0 = frame[fb + 0 * HW + p] * im;
    float f1 = frame[fb + 1 * HW + p] * im;
    float f2 = frame[fb + 2 * HW + p] * im;
    float f3 = frame[fb + 3 * HW + p] * im;

    #pragma unroll
    for (int cyi = 0; cyi < 2; ++cyi) {
        #pragma unroll
        for (int cxi = 0; cxi < 2; ++cxi) {
            int cx = fx + cxi;
            int cy = fy + cyi;
            if ((unsigned)cx >= (unsigned)W || (unsigned)cy >= (unsigned)H) continue;
            int ax = cx - sx; if (ax < 0) ax = -ax;
            int ay = cy - sy; if (ay < 0) ay = -ay;
            if (ax <= RAD && ay <= RAD) continue;   // covered by owner block
            float w = (cxi ? dx : 1.0f - dx) * (cyi ? dy : 1.0f - dy);
            int e = atomicAdd(ovf_cnt, 1);
            if (e < OVF_CAP) {
                float* ent = ovf_buf + (size_t)e * 8;
                ent[0] = __int_as_float(b * HW + cy * W + cx);
                ent[1] = f0 * w;
                ent[2] = f1 * w;
                ent[3] = f2 * w;
                ent[4] = f3 * w;
                ent[5] = im * w;
            }
        }
    }
}

// ---- main: per-output-tile float4 gather-scatter + fused normalize
__global__ __launch_bounds__(256) void splat_main(
    const float* __restrict__ frame,
    const float* __restrict__ flow,
    const float* __restrict__ imp,
    float* __restrict__ out,
    const int* __restrict__ ovf_cnt,
    const float* __restrict__ ovf_buf)
{
    __shared__ float lf[5 * 1024];   // 20480 B -> 8 blocks/CU

    const int tid = threadIdx.x;
    const int x0 = blockIdx.x * TX;
    const int y0 = blockIdx.y * TY;
    const int b  = blockIdx.z;

    for (int i = tid; i < 5 * 1024; i += 256) lf[i] = 0.0f;
    __syncthreads();

    const float* fxp = flow + (size_t)b * 2 * HW;
    const float* fyp = fxp + HW;
    const float* imp_p = imp + (size_t)b * HW;
    const float* c0p = frame + (size_t)b * CHW;
    const float* c1p = c0p + HW;
    const float* c2p = c1p + HW;
    const float* c3p = c2p + HW;

    #pragma unroll
    for (int it = 0; it < 2; ++it) {
        int q = tid + it * 256;
        if (q < NQUAD) {
            int r = q / QX;                 // 0..41
            int c = q - r * QX;             // 0..11
            int sy = y0 - RAD + r;
            int sx0 = x0 - 8 + 4 * c;
            int p = sy * W + sx0;
            int pc = p < 0 ? 0 : (p > HW - 4 ? HW - 4 : p);
            // W % 4 == 0 and sx0 % 4 == 0 -> all 4 lanes share validity
            bool qv = ((unsigned)sy < (unsigned)H) & ((unsigned)sx0 < (unsigned)W);

            float4 vfx = *(const float4*)(fxp + pc);
            float4 vfy = *(const float4*)(fyp + pc);
            float4 vim = *(const float4*)(imp_p + pc);
            float4 v0  = *(const float4*)(c0p + pc);
            float4 v1  = *(const float4*)(c1p + pc);
            float4 v2  = *(const float4*)(c2p + pc);
            float4 v3  = *(const float4*)(c3p + pc);

            float aflx[4] = {vfx.x, vfx.y, vfx.z, vfx.w};
            float afly[4] = {vfy.x, vfy.y, vfy.z, vfy.w};
            float aim [4] = {vim.x, vim.y, vim.z, vim.w};
            float a0  [4] = {v0.x,  v0.y,  v0.z,  v0.w};
            float a1  [4] = {v1.x,  v1.y,  v1.z,  v1.w};
            float a2  [4] = {v2.x,  v2.y,  v2.z,  v2.w};
            float a3  [4] = {v3.x,  v3.y,  v3.z,  v3.w};

            #pragma unroll
            for (int k = 0; k < 4; ++k) {
                int sx = sx0 + k;
                float im = qv ? __expf(aim[k]) : 0.0f;
                float tx = (float)sx + aflx[k];
                float ty = (float)sy + afly[k];
                float fxf = floorf(tx);
                float fyf = floorf(ty);
                float dx = tx - fxf;
                float dy = ty - fyf;
                int fxi = (int)fxf;
                int fyi = (int)fyf;
                float g0 = a0[k] * im;
                float g1 = a1[k] * im;
                float g2 = a2[k] * im;
                float g3 = a3[k] * im;

                #pragma unroll
                for (int cyi = 0; cyi < 2; ++cyi) {
                    #pragma unroll
                    for (int cxi = 0; cxi < 2; ++cxi) {
                        int cx = fxi + cxi;
                        int cy = fyi + cyi;
                        unsigned lxc = (unsigned)(cx - x0);
                        unsigned lyc = (unsigned)(cy - y0);
                        int ax = cx - sx; if (ax < 0) ax = -ax;
                        int ay = cy - sy; if (ay < 0) ay = -ay;
                        bool in = qv & (lxc < (unsigned)TX) & (lyc < (unsigned)TY)
                                     & (ax <= RAD) & (ay <= RAD);
                        if (in) {
                            float w = (cxi ? dx : 1.0f - dx) * (cyi ? dy : 1.0f - dy);
                            int cell = (int)lyc * TX + (int)lxc;
                            lds_add(&lf[0 * 1024 + cell], g0 * w);
                            lds_add(&lf[1 * 1024 + cell], g1 * w);
                            lds_add(&lf[2 * 1024 + cell], g2 * w);
                            lds_add(&lf[3 * 1024 + cell], g3 * w);
                            lds_add(&lf[4 * 1024 + cell], im * w);
                        }
                    }
                }
            }
        }
    }

    // merge overflow entries that land in my tile
    int cnt = *ovf_cnt;
    if (cnt > OVF_CAP) cnt = OVF_CAP;
    for (int e = tid; e < cnt; e += 256) {
        const float* ent = ovf_buf + (size_t)e * 8;
        int bcell = __float_as_int(ent[0]);
        int eb = bcell / HW;
        if (eb != b) continue;
        int rem = bcell - eb * HW;
        int cy = rem / W;
        int cx = rem - cy * W;
        unsigned lxc = (unsigned)(cx - x0);
        unsigned lyc = (unsigned)(cy - y0);
        if (lxc >= (unsigned)TX || lyc >= (unsigned)TY) continue;
        int cell = (int)lyc * TX + (int)lxc;
        lds_add(&lf[0 * 1024 + cell], ent[1]);
        lds_add(&lf[1 * 1024 + cell], ent[2]);
        lds_add(&lf[2 * 1024 + cell], ent[3]);
        lds_add(&lf[3 * 1024 + cell], ent[4]);
        lds_add(&lf[4 * 1024 + cell], ent[5]);
    }

    __syncthreads();

    // fused normalize + store
    #pragma unroll
    for (int n = 0; n < (TX * TY) / 256; ++n) {
        int i = tid + n * 256;
        int cy = i >> 5;
        int cx = i & 31;
        float inv = 1.0f / (lf[4 * 1024 + i] + EPS);
        size_t o = (size_t)b * CHW + (size_t)(y0 + cy) * W + (x0 + cx);
        out[o + 0 * HW] = lf[0 * 1024 + i] * inv;
        out[o + 1 * HW] = lf[1 * 1024 + i] * inv;
        out[o + 2 * HW] = lf[2 * 1024 + i] * inv;
        out[o + 3 * HW] = lf[3 * 1024 + i] * inv;
    }
}

extern "C" void kernel_launch(void* const* d_in, const int* in_sizes, int n_in,
                              void* d_out, int out_size, void* d_ws, size_t ws_size,
                              hipStream_t stream) {
    const float* frame = (const float*)d_in[0];
    const float* flow  = (const float*)d_in[1];
    const float* imp   = (const float*)d_in[2];
    float* out = (float*)d_out;

    int*   ovf_cnt = (int*)d_ws;
    float* ovf_buf = (float*)((char*)d_ws + 16);

    hipMemsetAsync(d_ws, 0, 16, stream);   // just the counter

    outlier_pass<<<(NPIX + 255) / 256, 256, 0, stream>>>(frame, flow, imp, ovf_cnt, ovf_buf);

    dim3 grid(W / TX, H / TY, B);   // 30 x 16 x 8
    splat_main<<<grid, 256, 0, stream>>>(frame, flow, imp, out, ovf_cnt, ovf_buf);
}